// Round 6
// baseline (244.543 us; speedup 1.0000x reference)
//
#include <hip/hip_runtime.h>
#include <math.h>

#define B_DIM 256
#define T_DIM 8192
#define BLOCK 256
#define NSLOT 256
#define ROWS_TOT (B_DIM * T_DIM)         // 2,097,152 rows
#define NF4  (ROWS_TOT * 3)
#define TILE_ROWS 256
#define NTILES (ROWS_TOT / TILE_ROWS)    // 8192
#define GRID 1024
#define TPB (NTILES / GRID)              // 8 tiles per block, contiguous range

// LDS buffer layout (float4 units), 28672 B per buffer:
//   [0,768)      pred rows R..R+255   (12 KB)
//   [768,1536)   gt   rows R..R+255   (12 KB)
//   [1536,1792)  phase floats (3072B) + gt_phase ints (1024B)
#define L_GT   768
#define L_PHG  1536
#define BUF_F4 1792

// DMA staging via global_load_lds (no VGPR round-trip). Per tile per wave:
// exactly 7 DMA instructions -> counted s_waitcnt vmcnt(7) keeps the next
// tile's loads in flight across raw s_barrier (no __syncthreads in loop,
// so no compiler-forced vmcnt(0) drain). 2x28KB double buffer, 2 blocks/CU
// -> ~56KB outstanding per CU vs ~2KB in all previous rounds.
// ws layout: NSLOT x 8 doubles: 0:sse+12*nll 1:coher_sum 2:coher_cnt 3:pen2 4:velsq 5:accsq

__device__ __forceinline__ void dma16(const void* g, void* l) {
    __builtin_amdgcn_global_load_lds(
        (const __attribute__((address_space(1))) void*)g,
        (__attribute__((address_space(3))) void*)l, 16, 0, 0);
}

__device__ __forceinline__ void stage_tile(int R, int tid, float4* buf,
    const float4* __restrict__ pred4, const float4* __restrict__ gt4,
    const float*  __restrict__ ph,    const int*    __restrict__ gtp)
{
    const char* gp = (const char*)(pred4 + (size_t)R * 3);
    const char* gg = (const char*)(gt4   + (size_t)R * 3);
    char* lb = (char*)buf;
    const int o = tid * 16;
    dma16(gp + o,        lb + o);
    dma16(gp + 4096 + o, lb + 4096 + o);
    dma16(gp + 8192 + o, lb + 8192 + o);
    dma16(gg + o,        lb + 12288 + o);
    dma16(gg + 4096 + o, lb + 16384 + o);
    dma16(gg + 8192 + o, lb + 20480 + o);
    const char* gm = (tid < 192)
        ? ((const char*)(ph + (size_t)R * 3) + o)
        : ((const char*)(gtp + R) + (o - 3072));
    dma16(gm, lb + 24576 + o);
}

struct Bnd {                 // boundary rows R+256, R+257 (threads 254/255 only)
    float4 e0a, e0b, e0c;    // pred row R+256
    float4 e1a, e1b, e1c;    // pred row R+257
    float  q0, q1, q2;       // phase row R+256
};

__device__ __forceinline__ void load_bnd(int R, int tid, Bnd &b,
    const float4* __restrict__ pred4, const float* __restrict__ ph)
{
    if (tid >= BLOCK - 2) {
        int r1 = R + 256, r2 = R + 257;
        if (r1 >= ROWS_TOT) r1 = R;          // safe addr; masked by v1/v2 later
        if (r2 >= ROWS_TOT) r2 = R;
        const float4* p1 = pred4 + (size_t)r1 * 3;
        const float4* p2 = pred4 + (size_t)r2 * 3;
        b.e0a = p1[0]; b.e0b = p1[1]; b.e0c = p1[2];
        b.e1a = p2[0]; b.e1b = p2[1]; b.e1c = p2[2];
        const float* pp = ph + (size_t)r1 * 3;
        b.q0 = pp[0]; b.q1 = pp[1]; b.q2 = pp[2];
    }
}

__device__ __forceinline__ float pen_term(float s) {
    float d = fmaxf(sqrtf(s) - 10.0f, 0.0f);
    return d * d;
}
__device__ __forceinline__ void argmax3(float l0, float l1, float l2, int &p, float &m) {
    p = 0; m = l0;
    if (l1 > m) { m = l1; p = 1; }
    if (l2 > m) { m = l2; p = 2; }
}
__device__ __forceinline__ float nll3(float l0, float l1, float l2, int g) {
    float mx = fmaxf(l0, fmaxf(l1, l2));
    float s = __expf(l0 - mx) + __expf(l1 - mx) + __expf(l2 - mx);
    float sel = (g == 0) ? l0 : ((g == 1) ? l1 : l2);
    return mx + __logf(s) - sel;
}
__device__ __forceinline__ void sse4(const float4 &a, const float4 &g, float &s) {
    float d;
    d = a.x - g.x; s = fmaf(d, d, s);  d = a.y - g.y; s = fmaf(d, d, s);
    d = a.z - g.z; s = fmaf(d, d, s);  d = a.w - g.w; s = fmaf(d, d, s);
}
__device__ __forceinline__ void vel12(const float4 &p0a, const float4 &p0b, const float4 &p0c,
                                      const float4 &p1a, const float4 &p1b, const float4 &p1c,
                                      float &velsq, float &pen2) {
    float t;
    t = p1a.x - p0a.x; const float q0  = t * t;
    t = p1a.y - p0a.y; const float q1  = t * t;
    t = p1a.z - p0a.z; const float q2  = t * t;
    t = p1a.w - p0a.w; const float q3  = t * t;
    t = p1b.x - p0b.x; const float q4  = t * t;
    t = p1b.y - p0b.y; const float q5  = t * t;
    t = p1b.z - p0b.z; const float q6  = t * t;
    t = p1b.w - p0b.w; const float q7  = t * t;
    t = p1c.x - p0c.x; const float q8  = t * t;
    t = p1c.y - p0c.y; const float q9  = t * t;
    t = p1c.z - p0c.z; const float q10 = t * t;
    t = p1c.w - p0c.w; const float q11 = t * t;
    velsq += (q0 + q1 + q2 + q3) + (q4 + q5 + q6 + q7) + (q8 + q9 + q10 + q11);
    pen2  += pen_term(q0 + q1 + q2) + pen_term(q3 + q4 + q5)
           + pen_term(q6 + q7 + q8) + pen_term(q9 + q10 + q11);
}
__device__ __forceinline__ void acc4(const float4 &r0, const float4 &r1, const float4 &r2, float &accsq) {
    float a;
    a = r2.x - 2.0f * r1.x + r0.x; accsq = fmaf(a, a, accsq);
    a = r2.y - 2.0f * r1.y + r0.y; accsq = fmaf(a, a, accsq);
    a = r2.z - 2.0f * r1.z + r0.z; accsq = fmaf(a, a, accsq);
    a = r2.w - 2.0f * r1.w + r0.w; accsq = fmaf(a, a, accsq);
}

__global__ __launch_bounds__(BLOCK) void combined_loss_main(
    const float4* __restrict__ pred4,
    const float*  __restrict__ ph,
    const float4* __restrict__ gt4,
    const int*    __restrict__ gt_phase,
    double* __restrict__ ws)
{
    __shared__ float4 lds[2][BUF_F4];
    __shared__ float  s_red[4][6];

    const int tid = threadIdx.x;
    const int blk = blockIdx.x;
    const int t0  = blk * TPB;

    float sse = 0.f, nllv = 0.f, csum = 0.f, ccnt = 0.f;
    float pen2 = 0.f, velsq = 0.f, accsq = 0.f;

    Bnd bA, bB;
    // prologue: boundary regs first (older than DMA -> drained by vmcnt(7)),
    // then tile 0's 7 DMA instructions.
    load_bnd(t0 * TILE_ROWS, tid, bA, pred4, ph);
    stage_tile(t0 * TILE_ROWS, tid, lds[0], pred4, gt4, ph, gt_phase);

    for (int it = 0; it < TPB; ++it) {
        const int R = (t0 + it) * TILE_ROWS;
        float4* buf = lds[it & 1];

        if (it + 1 < TPB) {
            const int Rn = (t0 + it + 1) * TILE_ROWS;
            load_bnd(Rn, tid, bB, pred4, ph);
            stage_tile(Rn, tid, lds[(it + 1) & 1], pred4, gt4, ph, gt_phase);
            asm volatile("s_waitcnt vmcnt(7)" ::: "memory");   // tile it done; next 7 in flight
        } else {
            asm volatile("s_waitcnt vmcnt(0)" ::: "memory");
        }
        asm volatile("s_barrier" ::: "memory");                // all waves staged tile it

        // ---------------- compute tile it from LDS ----------------
        {
            const int row_g = R + tid;
            const int t  = row_g & (T_DIM - 1);
            const bool v1 = t < (T_DIM - 1);
            const bool v2 = t < (T_DIM - 2);

            const float4* sp = buf;
            const float4* sg = buf + L_GT;
            const float*  sf = (const float*)(buf + L_PHG);
            const int*    sgt = (const int*)(sf + 768);
            const int b3 = 3 * tid;

            const float4 r0a = sp[b3], r0b = sp[b3 + 1], r0c = sp[b3 + 2];
            const float4 g0a = sg[b3], g0b = sg[b3 + 1], g0c = sg[b3 + 2];

            float4 r1a, r1b, r1c, r2a, r2b, r2c;
            if (tid < BLOCK - 2) {
                r1a = sp[b3 + 3]; r1b = sp[b3 + 4]; r1c = sp[b3 + 5];
                r2a = sp[b3 + 6]; r2b = sp[b3 + 7]; r2c = sp[b3 + 8];
            } else if (tid == BLOCK - 2) {
                r1a = sp[b3 + 3]; r1b = sp[b3 + 4]; r1c = sp[b3 + 5];
                r2a = bA.e0a;     r2b = bA.e0b;     r2c = bA.e0c;
            } else {
                r1a = bA.e0a;     r1b = bA.e0b;     r1c = bA.e0c;
                r2a = bA.e1a;     r2b = bA.e1b;     r2c = bA.e1c;
            }

            sse4(r0a, g0a, sse); sse4(r0b, g0b, sse); sse4(r0c, g0c, sse);
            if (v1) vel12(r0a, r0b, r0c, r1a, r1b, r1c, velsq, pen2);
            if (v2) {
                acc4(r0a, r1a, r2a, accsq);
                acc4(r0b, r1b, r2b, accsq);
                acc4(r0c, r1c, r2c, accsq);
            }

            const float p00 = sf[b3], p01 = sf[b3 + 1], p02 = sf[b3 + 2];
            float p10, p11, p12;
            if (tid < BLOCK - 1) { p10 = sf[b3 + 3]; p11 = sf[b3 + 4]; p12 = sf[b3 + 5]; }
            else                 { p10 = bA.q0;      p11 = bA.q1;      p12 = bA.q2; }

            nllv += nll3(p00, p01, p02, sgt[tid]);
            if (v1) {
                int pP, pN; float mP, mN;
                argmax3(p00, p01, p02, pP, mP);
                argmax3(p10, p11, p12, pN, mN);
                const int mask = (pP == 0) ? 4 : ((pP == 1) ? 1 : 3);  // illegal: (0,2),(1,0),(2,0),(2,1)
                if ((mask >> pN) & 1) { csum += mN * mN; ccnt += 1.f; }
            }
        }

        asm volatile("s_waitcnt lgkmcnt(0)" ::: "memory");     // my LDS reads landed
        asm volatile("s_barrier" ::: "memory");                // all waves done reading buf
        bA = bB;
    }

    // ---------------- reduce: 6 chains (sse + 12*nll folded) ----------------
    float vals[6] = { fmaf(12.0f, nllv, sse), csum, ccnt, pen2, velsq, accsq };
    #pragma unroll
    for (int off = 32; off > 0; off >>= 1) {
        #pragma unroll
        for (int q = 0; q < 6; ++q)
            vals[q] += __shfl_down(vals[q], off, 64);
    }
    const int wave = tid >> 6, lane = tid & 63;
    if (lane == 0) {
        #pragma unroll
        for (int q = 0; q < 6; ++q) s_red[wave][q] = vals[q];
    }
    __syncthreads();
    if (tid < 6) {
        const double acc = (double)s_red[0][tid] + (double)s_red[1][tid]
                         + (double)s_red[2][tid] + (double)s_red[3][tid];
        atomicAdd(&ws[(size_t)(blk & (NSLOT - 1)) * 8 + tid], acc);
    }
}

__global__ __launch_bounds__(256) void combined_loss_final(
    const double* __restrict__ ws, float* __restrict__ out)
{
    __shared__ double sred[4][6];
    const int tid = threadIdx.x;
    double v[6];
    #pragma unroll
    for (int q = 0; q < 6; ++q) v[q] = ws[(size_t)tid * 8 + q];
    #pragma unroll
    for (int off = 32; off > 0; off >>= 1) {
        #pragma unroll
        for (int q = 0; q < 6; ++q)
            v[q] += __shfl_down(v[q], off, 64);
    }
    const int wave = tid >> 6, lane = tid & 63;
    if (lane == 0) {
        #pragma unroll
        for (int q = 0; q < 6; ++q) sred[wave][q] = v[q];
    }
    __syncthreads();
    if (tid == 0) {
        double s[6];
        #pragma unroll
        for (int q = 0; q < 6; ++q)
            s[q] = sred[0][q] + sred[1][q] + sred[2][q] + sred[3][q];
        const double robot_phase = s[0] / (double)((size_t)B_DIM * T_DIM * 12);
        const double coher = (s[2] > 0.0) ? (s[1] / fmax(s[2], 1.0)) : 0.0;
        const double speed = 5.0  * (s[3] / (double)((size_t)B_DIM * (T_DIM - 1) * 4));
        const double vel   = 0.05 * (s[4] / (double)((size_t)B_DIM * (T_DIM - 1) * 12));
        const double acc   = 0.01 * (s[5] / (double)((size_t)B_DIM * (T_DIM - 2) * 12));
        out[0] = (float)(robot_phase + 10.0 * coher + speed + vel + acc);
    }
}

extern "C" void kernel_launch(void* const* d_in, const int* in_sizes, int n_in,
                              void* d_out, int out_size, void* d_ws, size_t ws_size,
                              hipStream_t stream)
{
    const float4* pred4      = (const float4*)d_in[0];
    const float*  pred_phase = (const float*)d_in[1];
    const float4* gt4        = (const float4*)d_in[2];
    const int*    gt_phase   = (const int*)d_in[3];
    double* ws  = (double*)d_ws;
    float*  out = (float*)d_out;

    hipMemsetAsync(d_ws, 0, (size_t)NSLOT * 8 * sizeof(double), stream);

    combined_loss_main<<<dim3(GRID), BLOCK, 0, stream>>>(pred4, pred_phase, gt4, gt_phase, ws);
    combined_loss_final<<<1, 256, 0, stream>>>(ws, out);
}